// Round 8
// baseline (1078.978 us; speedup 1.0000x reference)
//
#include <hip/hip_runtime.h>

#define N_NODES_C 100000
#define N_GRAPHS_C 128

typedef __attribute__((ext_vector_type(8))) __bf16 bf16x8;
typedef __attribute__((ext_vector_type(4))) float f32x4;

__device__ __forceinline__ f32x4 mfma16(bf16x8 a, bf16x8 b, f32x4 c) {
    return __builtin_amdgcn_mfma_f32_16x16x32_bf16(a, b, c, 0, 0, 0);
}

// split two fp32 into packed bf16 hi-pair and lo-pair (low element in low 16 bits)
__device__ __forceinline__ void split2(float a, float b, unsigned& hi, unsigned& lo) {
    unsigned ua = __float_as_uint(a), ub = __float_as_uint(b);
    unsigned ha = ua & 0xFFFF0000u, hb = ub & 0xFFFF0000u;
    float la = a - __uint_as_float(ha), lb = b - __uint_as_float(hb);
    unsigned lpa = __float_as_uint(la) & 0xFFFF0000u;
    unsigned lpb = __float_as_uint(lb) & 0xFFFF0000u;
    hi = (ha >> 16) | hb;
    lo = (lpa >> 16) | lpb;
}

// ---------------- CSR build ----------------
__global__ void hist_kernel(const int* __restrict__ ei, int E, int* __restrict__ deg) {
    int i = blockIdx.x * blockDim.x + threadIdx.x;
    if (i < E) atomicAdd(&deg[ei[E + i]], 1);   // dst row of edge_index
}

__global__ void scan1_kernel(const int* __restrict__ deg, int N,
                             int* __restrict__ tmp, int* __restrict__ bsum) {
    __shared__ int sh[512];
    int t = threadIdx.x;
    int i = blockIdx.x * 512 + t;
    int v = (i < N) ? deg[i] : 0;
    sh[t] = v;
    __syncthreads();
    for (int off = 1; off < 512; off <<= 1) {
        int add = (t >= off) ? sh[t - off] : 0;
        __syncthreads();
        sh[t] += add;
        __syncthreads();
    }
    if (i < N) tmp[i] = sh[t] - v;
    if (t == 511) bsum[blockIdx.x] = sh[511];
}

__global__ void scan2_kernel(int* bsum, int nb) {
    if (threadIdx.x == 0 && blockIdx.x == 0) {
        int run = 0;
        for (int j = 0; j < nb; ++j) { int v = bsum[j]; bsum[j] = run; run += v; }
    }
}

__global__ void scan3_kernel(const int* __restrict__ tmp, const int* __restrict__ bsum,
                             int N, int* __restrict__ rowp, int* __restrict__ rowpm) {
    int i = blockIdx.x * 512 + threadIdx.x;
    if (i < N) {
        int v = tmp[i] + bsum[blockIdx.x];
        rowp[i] = v;
        rowpm[i] = v;          // mutable copy consumed by fill as cursor
    }
}

// dst-range passes: pass p touches only dst in [p*8192,(p+1)*8192) -> csr writes and
// rowpm atomics confined to an L2-resident window; ei re-reads served by L3.
#define FILL_EPT 8
__global__ void fill_kernel(const int* __restrict__ ei, int E,
                            int* __restrict__ rowpm, int* __restrict__ csr) {
    int p = blockIdx.y;
    int base = blockIdx.x * 256 * FILL_EPT + threadIdx.x;
#pragma unroll
    for (int k = 0; k < FILL_EPT; ++k) {
        int i = base + k * 256;
        if (i < E) {
            int d = ei[E + i];
            if ((d >> 13) == p) {
                int pos = atomicAdd(&rowpm[d], 1);
                csr[pos] = ei[i];                    // src row
            }
        }
    }
}

// ---------------- weight prep: split fp32 W -> bf16 hi/lo, pre-swizzled LDS image ----
__global__ void wprep_kernel(const float* __restrict__ Wrel, const float* __restrict__ Wroot,
                             int KH, unsigned* __restrict__ img) {
    int cid = blockIdx.x;          // chunk
    int col = threadIdx.x;         // 0..127 (output channel)
    int key = (col >> 1) & 3;
    unsigned hiw[16], low[16];
#pragma unroll 4
    for (int p = 0; p < 16; ++p) {
        int k0 = cid * 32 + p * 2;
        float v0 = (k0 < KH) ? Wrel[col * KH + k0] : Wroot[col * KH + k0 - KH];
        float v1 = (k0 + 1 < KH) ? Wrel[col * KH + k0 + 1] : Wroot[col * KH + k0 + 1 - KH];
        split2(v0, v1, hiw[p], low[p]);
    }
    unsigned* cb = img + (size_t)cid * 4096;
#pragma unroll 4
    for (int p = 0; p < 16; ++p) {
        int s = p >> 2, w = p & 3;
        int sp = s ^ key;
        cb[col * 16 + sp * 4 + w] = hiw[p];
        cb[2048 + col * 16 + sp * 4 + w] = low[p];
    }
}

// ---------------- FUSED layer: gather + split-bf16 dual-GEMM + bias/ReLU ----------------
// Block: 256 thr (4 waves) handles 64 dst nodes x 128 outs.
// Phase 1: each wave gathers fp32 neighbor-sums for its 16 nodes (registers),
//          splits to bf16 hi/lo and writes chunk-major swizzled LDS (sAgg).
// Phase 2: K-loop over 32-wide chunks: first NCA chunks read A from sAgg,
//          rest stream x (root term) via dbuf sX; W streamed via dbuf sW.
template <int KH, bool RELU>
__global__ __launch_bounds__(256, 2) void fused_kernel(
    const float* __restrict__ xin,
    const int* __restrict__ rowp, const int* __restrict__ degv,
    const int* __restrict__ csrc,
    const unsigned* __restrict__ wimg, const float* __restrict__ bias,
    float* __restrict__ hout, int nNodes)
{
    constexpr int NC  = (2 * KH) / 32;   // total K chunks
    constexpr int NCA = KH / 32;         // chunks served from sAgg
    constexpr int RS  = KH / 4;          // float4s per feature row
    constexpr int EPW = 64 / RS;         // edges per wave-instr (2 or 4)
    __shared__ unsigned sAgg[NCA * 2048];   // per chunk: hi[64*16] | lo[64*16]
    __shared__ unsigned sW[2][4096];        // hi[128*16] | lo[128*16]
    __shared__ unsigned sX[2][2048];        // hi[64*16]  | lo[64*16]
    const int t = threadIdx.x;
    const int nb0 = blockIdx.x * 64;
    const int lane = t & 63, wv = t >> 6;

    // ---- W chunk-0 prefetch into regs (in flight during gather) ----
    uint4 vw[4];
    {
        const uint4* ws = (const uint4*)wimg + t * 4;
#pragma unroll
        for (int q = 0; q < 4; ++q) vw[q] = ws[q];
    }

    // ---- Phase 1: gather (wave-private rows) ----
    {
        const float4* x4 = (const float4*)xin;
        const int grp = lane / RS;
        const int f4 = lane & (RS - 1);
        for (int ni = 0; ni < 16; ++ni) {
            const int node = nb0 + wv * 16 + ni;
            float4 a[8];
#pragma unroll
            for (int q = 0; q < 8; ++q) a[q] = make_float4(0.f, 0.f, 0.f, 0.f);
            if (node < nNodes) {
                int start = rowp[node], deg = degv[node];
                for (int base = 0; base < deg; base += 64) {
                    int cnt = min(64, deg - base);
                    int sid = (lane < cnt) ? csrc[start + base + lane] : 0;
                    int j = 0;
                    for (; j + 8 * EPW <= cnt; j += 8 * EPW) {
                        int n[8];
#pragma unroll
                        for (int q = 0; q < 8; ++q) n[q] = __shfl(sid, j + q * EPW + grp);
                        float4 v[8];
#pragma unroll
                        for (int q = 0; q < 8; ++q) v[q] = x4[(size_t)n[q] * RS + f4];
#pragma unroll
                        for (int q = 0; q < 8; ++q) {
                            a[q].x += v[q].x; a[q].y += v[q].y;
                            a[q].z += v[q].z; a[q].w += v[q].w;
                        }
                    }
                    for (; j + EPW <= cnt; j += EPW) {
                        int n0 = __shfl(sid, j + grp);
                        float4 v = x4[(size_t)n0 * RS + f4];
                        a[0].x += v.x; a[0].y += v.y; a[0].z += v.z; a[0].w += v.w;
                    }
                    for (; j < cnt; ++j) {
                        int n0 = __shfl(sid, j);
                        if (grp == 0) {
                            float4 v = x4[(size_t)n0 * RS + f4];
                            a[0].x += v.x; a[0].y += v.y; a[0].z += v.z; a[0].w += v.w;
                        }
                    }
                }
            }
            float4 tot;
            tot.x = ((a[0].x+a[1].x)+(a[2].x+a[3].x)) + ((a[4].x+a[5].x)+(a[6].x+a[7].x));
            tot.y = ((a[0].y+a[1].y)+(a[2].y+a[3].y)) + ((a[4].y+a[5].y)+(a[6].y+a[7].y));
            tot.z = ((a[0].z+a[1].z)+(a[2].z+a[3].z)) + ((a[4].z+a[5].z)+(a[6].z+a[7].z));
            tot.w = ((a[0].w+a[1].w)+(a[2].w+a[3].w)) + ((a[4].w+a[5].w)+(a[6].w+a[7].w));
            if (RS == 16) {
                tot.x += __shfl_xor(tot.x, 16); tot.y += __shfl_xor(tot.y, 16);
                tot.z += __shfl_xor(tot.z, 16); tot.w += __shfl_xor(tot.w, 16);
            }
            tot.x += __shfl_xor(tot.x, 32); tot.y += __shfl_xor(tot.y, 32);
            tot.z += __shfl_xor(tot.z, 32); tot.w += __shfl_xor(tot.w, 32);
            if (grp < 2) {
                unsigned h0, l0, h1, l1;
                split2(tot.x, tot.y, h0, l0);
                split2(tot.z, tot.w, h1, l1);
                int row = wv * 16 + ni;
                int key = (row >> 1) & 3;
                int c = f4 >> 3;                 // which 32-k chunk
                int u = (2 * f4) & 15;           // uint index within chunk row (even)
                int sp = (u >> 2) ^ key;         // swizzled slot
                unsigned* dst = &sAgg[c * 2048 + grp * 1024 + row * 16 + sp * 4 + (u & 3)];
                dst[0] = (grp == 0) ? h0 : l0;
                dst[1] = (grp == 0) ? h1 : l1;
            }
        }
    }

    // ---- staging helpers ----
    const int srow = t >> 2;             // 0..63 (node row)
    const int kq = t & 3;                // 8-k quarter of a 32-k chunk
    const int skey = (srow >> 1) & 3;
    const bool svalid = (nb0 + srow) < nNodes;
    float4 vx0, vx1;
    auto loadW = [&](int cix) {
        const uint4* ws = (const uint4*)(wimg + (size_t)cix * 4096) + t * 4;
#pragma unroll
        for (int q = 0; q < 4; ++q) vw[q] = ws[q];
    };
    auto loadX = [&](int cix) {
        int kofs = (cix - NCA) * 32 + kq * 8;
        if (svalid) {
            const float* p = &xin[(size_t)(nb0 + srow) * KH + kofs];
            vx0 = *(const float4*)p;
            vx1 = *(const float4*)(p + 4);
        } else {
            vx0 = make_float4(0.f, 0.f, 0.f, 0.f);
            vx1 = vx0;
        }
    };
    auto writeW = [&](int buf) {
        uint4* wd = (uint4*)&sW[buf][t * 16];
#pragma unroll
        for (int q = 0; q < 4; ++q) wd[q] = vw[q];
    };
    auto writeX = [&](int buf) {
        unsigned h[4], l[4];
        split2(vx0.x, vx0.y, h[0], l[0]); split2(vx0.z, vx0.w, h[1], l[1]);
        split2(vx1.x, vx1.y, h[2], l[2]); split2(vx1.z, vx1.w, h[3], l[3]);
        int sp = (kq ^ skey) * 4;
        *(uint4*)&sX[buf][srow * 16 + sp] = make_uint4(h[0], h[1], h[2], h[3]);
        *(uint4*)&sX[buf][1024 + srow * 16 + sp] = make_uint4(l[0], l[1], l[2], l[3]);
    };

    // ---- Phase 2: MFMA K-loop ----
    const int r15 = lane & 15, hi4 = lane >> 4;
    const int ckey = (r15 >> 1) & 3;
    const int cslot = (hi4 ^ ckey) * 4;
    const int arow = (wv * 16 + r15) * 16;

    f32x4 acc[8];
#pragma unroll
    for (int j = 0; j < 8; ++j) acc[j] = (f32x4){0.f, 0.f, 0.f, 0.f};
    float bj[8];
#pragma unroll
    for (int j = 0; j < 8; ++j) bj[j] = bias[j * 16 + r15];

    writeW(0);
    if (NC > 1) { loadW(1); if (1 >= NCA) loadX(1); }
    __syncthreads();

#pragma unroll 1
    for (int cix = 0; cix < NC; ++cix) {
        const int cur = cix & 1;
        if (cix + 1 < NC) {
            writeW(cur ^ 1);                       // regs hold chunk cix+1
            if (cix + 1 >= NCA) writeX(cur ^ 1);
            if (cix + 2 < NC) {
                loadW(cix + 2);
                if (cix + 2 >= NCA) loadX(cix + 2);
            }
        }
        const unsigned* Ah = (cix < NCA) ? &sAgg[cix * 2048] : &sX[cur][0];
        const unsigned* W = sW[cur];
        bf16x8 ah = *(const bf16x8*)&Ah[arow + cslot];
        bf16x8 al = *(const bf16x8*)&Ah[1024 + arow + cslot];
#pragma unroll
        for (int j = 0; j < 8; ++j) {
            int cb = (j * 16 + r15) * 16;
            bf16x8 bh = *(const bf16x8*)&W[cb + cslot];
            bf16x8 bl = *(const bf16x8*)&W[2048 + cb + cslot];
            acc[j] = mfma16(ah, bh, acc[j]);
            acc[j] = mfma16(ah, bl, acc[j]);
            acc[j] = mfma16(al, bh, acc[j]);
        }
        __syncthreads();
    }

    // ---- epilogue ----
#pragma unroll
    for (int r = 0; r < 4; ++r) {
        int node = nb0 + wv * 16 + hi4 * 4 + r;
        if (node >= nNodes) continue;
        float* orow = &hout[(size_t)node * 128];
#pragma unroll
        for (int j = 0; j < 8; ++j) {
            float v = acc[j][r] + bj[j];
            if (RELU) v = fmaxf(v, 0.f);
            orow[j * 16 + r15] = v;
        }
    }
}

// ---------------- pooling (batch is SORTED: geometry, no atomics) ----------------
__global__ void bounds_kernel(const int* __restrict__ batch, int N, int* __restrict__ gstart) {
    int g = blockIdx.x * blockDim.x + threadIdx.x;
    if (g > N_GRAPHS_C) return;
    int lo = 0, hi = N;
    while (lo < hi) {
        int mid = (lo + hi) >> 1;
        if (batch[mid] < g) lo = mid + 1; else hi = mid;
    }
    gstart[g] = lo;
}

// one block per graph; 256 threads = 8 node-subsets x 32 float4-features
__global__ __launch_bounds__(256) void pool2_kernel(const float* __restrict__ h,
                                                    const int* __restrict__ gstart,
                                                    float* __restrict__ pooled) {
    int g = blockIdx.x;
    int f4 = threadIdx.x & 31;
    int sub = threadIdx.x >> 5;
    int s = gstart[g], e = gstart[g + 1];
    const float4* h4 = (const float4*)h;
    float4 acc = make_float4(0.f, 0.f, 0.f, 0.f);
    for (int n = s + sub; n < e; n += 8) {
        float4 v = h4[(size_t)n * 32 + f4];
        acc.x += v.x; acc.y += v.y; acc.z += v.z; acc.w += v.w;
    }
    __shared__ float4 sh[8][33];
    sh[sub][f4] = acc;
    __syncthreads();
    if (sub == 0) {
        float4 tot = acc;
#pragma unroll
        for (int q = 1; q < 8; ++q) {
            float4 v = sh[q][f4];
            tot.x += v.x; tot.y += v.y; tot.z += v.z; tot.w += v.w;
        }
        float inv = 1.0f / fmaxf((float)(e - s), 1.0f);
        tot.x *= inv; tot.y *= inv; tot.z *= inv; tot.w *= inv;
        ((float4*)pooled)[g * 32 + f4] = tot;
    }
}

__global__ void final_kernel(const float* __restrict__ pooled,
                             const float* __restrict__ Wlin, const float* __restrict__ blin,
                             float* __restrict__ out) {
    int idx = blockIdx.x * blockDim.x + threadIdx.x;   // 2048 = 128 x 16
    int g = idx >> 4, c = idx & 15;
    float s = 0.f;
    for (int k = 0; k < 128; ++k) s += pooled[g * 128 + k] * Wlin[c * 128 + k];
    out[idx] = s + blin[c];
}

// ---------------- launch ----------------
extern "C" void kernel_launch(void* const* d_in, const int* in_sizes, int n_in,
                              void* d_out, int out_size, void* d_ws, size_t ws_size,
                              hipStream_t stream) {
    const float* x      = (const float*)d_in[0];
    const int*   ei     = (const int*)d_in[1];
    const int*   batch  = (const int*)d_in[2];
    const float* W1_rel = (const float*)d_in[3];
    const float* b1     = (const float*)d_in[4];
    const float* W1_root= (const float*)d_in[5];
    const float* W2_rel = (const float*)d_in[6];
    const float* b2     = (const float*)d_in[7];
    const float* W2_root= (const float*)d_in[8];
    const float* W3_rel = (const float*)d_in[9];
    const float* b3     = (const float*)d_in[10];
    const float* W3_root= (const float*)d_in[11];
    const float* W_lin  = (const float*)d_in[12];
    const float* b_lin  = (const float*)d_in[13];
    float* out = (float*)d_out;

    const int N = in_sizes[2];          // 100000
    const int E = in_sizes[1] / 2;      // 1600000
    const int nb = (N + 511) / 512;

    char* base = (char*)d_ws;
    size_t off = 0;
    auto carve = [&](size_t bytes) -> void* {
        void* p = base + off;
        off = (off + bytes + 255) & ~(size_t)255;
        return p;
    };
    int*      deg    = (int*)carve((size_t)N * 4);
    int*      tmp    = (int*)carve((size_t)N * 4);
    int*      bsum   = (int*)carve(1024);
    int*      rowp   = (int*)carve((size_t)(N + 1) * 4);
    int*      rowpm  = (int*)carve((size_t)N * 4);
    int*      csr    = (int*)carve((size_t)E * 4);
    float*    hA     = (float*)carve((size_t)N * 128 * 4);
    float*    hB     = (float*)carve((size_t)N * 128 * 4);
    float*    pooled = (float*)carve((size_t)N_GRAPHS_C * 128 * 4);
    int*      gstart = (int*)carve((size_t)(N_GRAPHS_C + 1) * 4);
    unsigned* wimg1  = (unsigned*)carve((size_t)4 * 4096 * 4);   // 64 KB
    unsigned* wimg2  = (unsigned*)carve((size_t)8 * 4096 * 4);   // 128 KB
    unsigned* wimg3  = (unsigned*)carve((size_t)8 * 4096 * 4);   // 128 KB
    (void)ws_size;

    hipMemsetAsync(deg, 0, (size_t)N * 4, stream);

    // weight prep (tiny)
    wprep_kernel<<<4, 128, 0, stream>>>(W1_rel, W1_root, 64, wimg1);
    wprep_kernel<<<8, 128, 0, stream>>>(W2_rel, W2_root, 128, wimg2);
    wprep_kernel<<<8, 128, 0, stream>>>(W3_rel, W3_root, 128, wimg3);

    // CSR build
    hist_kernel<<<(E + 255) / 256, 256, 0, stream>>>(ei, E, deg);
    scan1_kernel<<<nb, 512, 0, stream>>>(deg, N, tmp, bsum);
    scan2_kernel<<<1, 64, 0, stream>>>(bsum, nb);
    scan3_kernel<<<nb, 512, 0, stream>>>(tmp, bsum, N, rowp, rowpm);
    const int npass = (N + 8191) >> 13;
    fill_kernel<<<dim3((E + 256 * FILL_EPT - 1) / (256 * FILL_EPT), npass), 256, 0, stream>>>(
        ei, E, rowpm, csr);

    // graph boundaries (batch sorted)
    bounds_kernel<<<1, 192, 0, stream>>>(batch, N, gstart);

    const int fGrid = (N + 63) / 64;

    // layer 1 (KH=64): gather x + [agg|x]·[W1_rel;W1_root]^T + b1, ReLU
    fused_kernel<64, true><<<fGrid, 256, 0, stream>>>(
        x, rowp, deg, csr, wimg1, b1, hA, N);

    // layer 2 (KH=128)
    fused_kernel<128, true><<<fGrid, 256, 0, stream>>>(
        hA, rowp, deg, csr, wimg2, b2, hB, N);

    // layer 3 (KH=128, no relu)
    fused_kernel<128, false><<<fGrid, 256, 0, stream>>>(
        hB, rowp, deg, csr, wimg3, b3, hA, N);

    // pooling + classifier (no atomics)
    pool2_kernel<<<N_GRAPHS_C, 256, 0, stream>>>(hA, gstart, pooled);
    final_kernel<<<8, 256, 0, stream>>>(pooled, W_lin, b_lin, out);
}

// Round 9
// 802.386 us; speedup vs baseline: 1.3447x; 1.3447x over previous
//
#include <hip/hip_runtime.h>

#define N_NODES_C 100000
#define N_GRAPHS_C 128

typedef __attribute__((ext_vector_type(8))) __bf16 bf16x8;
typedef __attribute__((ext_vector_type(4))) float f32x4;

__device__ __forceinline__ f32x4 mfma16(bf16x8 a, bf16x8 b, f32x4 c) {
    return __builtin_amdgcn_mfma_f32_16x16x32_bf16(a, b, c, 0, 0, 0);
}

// split two fp32 into packed bf16 hi-pair and lo-pair (low element in low 16 bits)
__device__ __forceinline__ void split2(float a, float b, unsigned& hi, unsigned& lo) {
    unsigned ua = __float_as_uint(a), ub = __float_as_uint(b);
    unsigned ha = ua & 0xFFFF0000u, hb = ub & 0xFFFF0000u;
    float la = a - __uint_as_float(ha), lb = b - __uint_as_float(hb);
    unsigned lpa = __float_as_uint(la) & 0xFFFF0000u;
    unsigned lpb = __float_as_uint(lb) & 0xFFFF0000u;
    hi = (ha >> 16) | hb;
    lo = (lpa >> 16) | lpb;
}

__device__ __forceinline__ void splitfrag(float4 v0, float4 v1, bf16x8& hi, bf16x8& lo) {
    unsigned h[4], l[4];
    split2(v0.x, v0.y, h[0], l[0]); split2(v0.z, v0.w, h[1], l[1]);
    split2(v1.x, v1.y, h[2], l[2]); split2(v1.z, v1.w, h[3], l[3]);
    uint4 uh = make_uint4(h[0], h[1], h[2], h[3]);
    uint4 ul = make_uint4(l[0], l[1], l[2], l[3]);
    hi = *(bf16x8*)&uh; lo = *(bf16x8*)&ul;
}

// ---------------- CSR build ----------------
__global__ void hist_kernel(const int* __restrict__ ei, int E, int* __restrict__ deg) {
    int i = blockIdx.x * blockDim.x + threadIdx.x;
    if (i < E) atomicAdd(&deg[ei[E + i]], 1);   // dst row of edge_index
}

__global__ void scan1_kernel(const int* __restrict__ deg, int N,
                             int* __restrict__ tmp, int* __restrict__ bsum) {
    __shared__ int sh[512];
    int t = threadIdx.x;
    int i = blockIdx.x * 512 + t;
    int v = (i < N) ? deg[i] : 0;
    sh[t] = v;
    __syncthreads();
    for (int off = 1; off < 512; off <<= 1) {
        int add = (t >= off) ? sh[t - off] : 0;
        __syncthreads();
        sh[t] += add;
        __syncthreads();
    }
    if (i < N) tmp[i] = sh[t] - v;
    if (t == 511) bsum[blockIdx.x] = sh[511];
}

__global__ void scan2_kernel(int* bsum, int nb) {
    if (threadIdx.x == 0 && blockIdx.x == 0) {
        int run = 0;
        for (int j = 0; j < nb; ++j) { int v = bsum[j]; bsum[j] = run; run += v; }
    }
}

__global__ void scan3_kernel(const int* __restrict__ tmp, const int* __restrict__ bsum,
                             int N, int* __restrict__ rowp, int* __restrict__ rowpm) {
    int i = blockIdx.x * 512 + threadIdx.x;
    if (i < N) {
        int v = tmp[i] + bsum[blockIdx.x];
        rowp[i] = v;
        rowpm[i] = v;          // mutable copy consumed by fill as cursor
    }
}

// dst-range passes: pass p touches only dst in [p*8192,(p+1)*8192) -> csr writes and
// rowpm atomics confined to an L2-resident window; ei re-reads served by L3.
#define FILL_EPT 8
__global__ void fill_kernel(const int* __restrict__ ei, int E,
                            int* __restrict__ rowpm, int* __restrict__ csr) {
    int p = blockIdx.y;
    int base = blockIdx.x * 256 * FILL_EPT + threadIdx.x;
#pragma unroll
    for (int k = 0; k < FILL_EPT; ++k) {
        int i = base + k * 256;
        if (i < E) {
            int d = ei[E + i];
            if ((d >> 13) == p) {
                int pos = atomicAdd(&rowpm[d], 1);
                csr[pos] = ei[i];                    // src row
            }
        }
    }
}

// ---------------- neighbor aggregation (float4 gather, multi-edge per wave) ------
template <int FIN>
__global__ __launch_bounds__(256) void agg_kernel(const float* __restrict__ xin,
                                                  const int* __restrict__ rowp,
                                                  const int* __restrict__ degv,
                                                  const int* __restrict__ csrc,
                                                  float* __restrict__ aggout, int nNodes) {
    int wave = blockIdx.x * 4 + (threadIdx.x >> 6);
    int lane = threadIdx.x & 63;
    if (wave >= nNodes) return;
    int start = rowp[wave];
    int deg = degv[wave];
    const float4* x4 = (const float4*)xin;
    constexpr int EPW = (FIN == 128) ? 2 : 4;       // edges per wave-iteration
    constexpr int RS = FIN / 4;                      // float4s per row (32 or 16)
    const int grp = lane / RS;                       // which edge in the group
    const int f4 = lane & (RS - 1);                  // float4 index within row

    float4 acc[8];
#pragma unroll
    for (int q = 0; q < 8; ++q) acc[q] = make_float4(0.f, 0.f, 0.f, 0.f);

    for (int base = 0; base < deg; base += 64) {
        int cnt = min(64, deg - base);
        int sid = (lane < cnt) ? csrc[start + base + lane] : 0;
        int j = 0;
        for (; j + 8 * EPW <= cnt; j += 8 * EPW) {   // 8*EPW edges in flight
            int n[8];
#pragma unroll
            for (int q = 0; q < 8; ++q) n[q] = __shfl(sid, j + q * EPW + grp);
            float4 v[8];
#pragma unroll
            for (int q = 0; q < 8; ++q) v[q] = x4[(size_t)n[q] * RS + f4];
#pragma unroll
            for (int q = 0; q < 8; ++q) {
                acc[q].x += v[q].x; acc[q].y += v[q].y;
                acc[q].z += v[q].z; acc[q].w += v[q].w;
            }
        }
        for (; j + EPW <= cnt; j += EPW) {
            int n0 = __shfl(sid, j + grp);
            float4 v = x4[(size_t)n0 * RS + f4];
            acc[0].x += v.x; acc[0].y += v.y; acc[0].z += v.z; acc[0].w += v.w;
        }
        for (; j < cnt; ++j) {                       // remainder: group 0 only
            int n0 = __shfl(sid, j);
            if (grp == 0) {
                float4 v = x4[(size_t)n0 * RS + f4];
                acc[0].x += v.x; acc[0].y += v.y; acc[0].z += v.z; acc[0].w += v.w;
            }
        }
    }
    float4 tot;
    tot.x = ((acc[0].x+acc[1].x)+(acc[2].x+acc[3].x)) + ((acc[4].x+acc[5].x)+(acc[6].x+acc[7].x));
    tot.y = ((acc[0].y+acc[1].y)+(acc[2].y+acc[3].y)) + ((acc[4].y+acc[5].y)+(acc[6].y+acc[7].y));
    tot.z = ((acc[0].z+acc[1].z)+(acc[2].z+acc[3].z)) + ((acc[4].z+acc[5].z)+(acc[6].z+acc[7].z));
    tot.w = ((acc[0].w+acc[1].w)+(acc[2].w+acc[3].w)) + ((acc[4].w+acc[5].w)+(acc[6].w+acc[7].w));
    if (FIN == 64) {
        tot.x += __shfl_xor(tot.x, 16); tot.y += __shfl_xor(tot.y, 16);
        tot.z += __shfl_xor(tot.z, 16); tot.w += __shfl_xor(tot.w, 16);
    }
    tot.x += __shfl_xor(tot.x, 32); tot.y += __shfl_xor(tot.y, 32);
    tot.z += __shfl_xor(tot.z, 32); tot.w += __shfl_xor(tot.w, 32);
    if (lane < RS)
        ((float4*)aggout)[(size_t)wave * RS + lane] = tot;
}

// ---------------- weight prep: frag-linear split-bf16 W image ----------------
// For chunk c, out-tile j, plane p (0=hi,1=lo): 1 KB block, lane l's bf16x8 at l*16B.
// Frag layout (m89): col = j*16 + (l&15), k = c*32 + (l>>4)*8 + e, pairs packed lo/hi.
__global__ void wprep_kernel(const float* __restrict__ Wrel, const float* __restrict__ Wroot,
                             int KH, unsigned* __restrict__ img) {
    int cj = blockIdx.x;               // c*8 + j
    int l = threadIdx.x;               // 0..63
    int c = cj >> 3, j = cj & 7;
    int col = j * 16 + (l & 15);
    int k0 = c * 32 + (l >> 4) * 8;
    const float* src = (k0 < KH) ? Wrel : Wroot;
    int kk = (k0 < KH) ? k0 : k0 - KH;
    unsigned h[4], lo[4];
#pragma unroll
    for (int q = 0; q < 4; ++q) {
        float a = src[col * KH + kk + 2 * q];
        float b = src[col * KH + kk + 2 * q + 1];
        split2(a, b, h[q], lo[q]);
    }
    *(uint4*)&img[((size_t)cj * 2 + 0) * 256 + l * 4] = make_uint4(h[0], h[1], h[2], h[3]);
    *(uint4*)&img[((size_t)cj * 2 + 1) * 256 + l * 4] = make_uint4(lo[0], lo[1], lo[2], lo[3]);
}

// ---------------- dual-GEMM transform: zero-LDS register-direct MFMA ----------------
// C[N x 128] = [agg | xin] * [Wrel;Wroot]^T + bias (split-bf16 3-product scheme).
// Block: 256 thr (4 waves) x 128 nodes; wave handles 32 rows (2 MFMA M-tiles).
// A-frags loaded per-lane from global (row=(l&15)+16*tile, k=hi4*8), split in-register.
// B-frags from frag-linear W image (coalesced 1KB/load, L2-resident). No LDS, no barriers.
template <int KTOT, bool RELU>
__global__ __launch_bounds__(256) void xform_kernel(
    const float* __restrict__ agg, const float* __restrict__ xin,
    const unsigned* __restrict__ wimg, const float* __restrict__ bias,
    float* __restrict__ hout, int nNodes)
{
    constexpr int KH = KTOT / 2;
    constexpr int NC = KTOT / 32;
    const int t = threadIdx.x;
    const int lane = t & 63, wv = t >> 6;
    const int r15 = lane & 15, hi4 = lane >> 4;
    const int nb0 = blockIdx.x * 128;
    const int row0 = nb0 + wv * 32 + r15;
    const int row1 = row0 + 16;
    const bool v0 = row0 < nNodes, v1 = row1 < nNodes;
    const float4 z4 = make_float4(0.f, 0.f, 0.f, 0.f);

    f32x4 acc[2][8];
#pragma unroll
    for (int g = 0; g < 2; ++g)
#pragma unroll
        for (int j = 0; j < 8; ++j) acc[g][j] = (f32x4){0.f, 0.f, 0.f, 0.f};
    float bj[8];
#pragma unroll
    for (int j = 0; j < 8; ++j) bj[j] = bias[j * 16 + r15];

#pragma unroll 1
    for (int c = 0; c < NC; ++c) {
        const float* srcA = (c * 32 < KH) ? agg : xin;
        const int ko = ((c * 32 < KH) ? (c * 32) : (c * 32 - KH)) + hi4 * 8;
        const float* p0 = &srcA[(size_t)row0 * KH + ko];
        const float* p1 = &srcA[(size_t)row1 * KH + ko];
        float4 a00 = v0 ? *(const float4*)p0 : z4;
        float4 a01 = v0 ? *(const float4*)(p0 + 4) : z4;
        float4 a10 = v1 ? *(const float4*)p1 : z4;
        float4 a11 = v1 ? *(const float4*)(p1 + 4) : z4;
        bf16x8 ah0, al0, ah1, al1;
        splitfrag(a00, a01, ah0, al0);
        splitfrag(a10, a11, ah1, al1);
        const unsigned* wc = wimg + (size_t)c * 4096;   // 8 j x 2 planes x 256 uints
#pragma unroll
        for (int j = 0; j < 8; ++j) {
            bf16x8 bh = *(const bf16x8*)&wc[(j * 2 + 0) * 256 + lane * 4];
            bf16x8 bl = *(const bf16x8*)&wc[(j * 2 + 1) * 256 + lane * 4];
            acc[0][j] = mfma16(ah0, bh, acc[0][j]);
            acc[1][j] = mfma16(ah1, bh, acc[1][j]);
            acc[0][j] = mfma16(ah0, bl, acc[0][j]);
            acc[1][j] = mfma16(ah1, bl, acc[1][j]);
            acc[0][j] = mfma16(al0, bh, acc[0][j]);
            acc[1][j] = mfma16(al1, bh, acc[1][j]);
        }
    }

    // epilogue: C col=lane&15 (out channel), row=(lane>>4)*4+reg (node) — m89-verified
#pragma unroll
    for (int g2 = 0; g2 < 2; ++g2) {
#pragma unroll
        for (int r = 0; r < 4; ++r) {
            int node = nb0 + wv * 32 + g2 * 16 + hi4 * 4 + r;
            if (node >= nNodes) continue;
            float* orow = &hout[(size_t)node * 128];
#pragma unroll
            for (int j = 0; j < 8; ++j) {
                float v = acc[g2][j][r] + bj[j];
                if (RELU) v = fmaxf(v, 0.f);
                orow[j * 16 + r15] = v;
            }
        }
    }
}

// ---------------- pooling (batch is SORTED: geometry, no atomics) ----------------
__global__ void bounds_kernel(const int* __restrict__ batch, int N, int* __restrict__ gstart) {
    int g = blockIdx.x * blockDim.x + threadIdx.x;
    if (g > N_GRAPHS_C) return;
    int lo = 0, hi = N;
    while (lo < hi) {
        int mid = (lo + hi) >> 1;
        if (batch[mid] < g) lo = mid + 1; else hi = mid;
    }
    gstart[g] = lo;
}

// one block per graph; 256 threads = 8 node-subsets x 32 float4-features
__global__ __launch_bounds__(256) void pool2_kernel(const float* __restrict__ h,
                                                    const int* __restrict__ gstart,
                                                    float* __restrict__ pooled) {
    int g = blockIdx.x;
    int f4 = threadIdx.x & 31;
    int sub = threadIdx.x >> 5;
    int s = gstart[g], e = gstart[g + 1];
    const float4* h4 = (const float4*)h;
    float4 acc = make_float4(0.f, 0.f, 0.f, 0.f);
    for (int n = s + sub; n < e; n += 8) {
        float4 v = h4[(size_t)n * 32 + f4];
        acc.x += v.x; acc.y += v.y; acc.z += v.z; acc.w += v.w;
    }
    __shared__ float4 sh[8][33];
    sh[sub][f4] = acc;
    __syncthreads();
    if (sub == 0) {
        float4 tot = acc;
#pragma unroll
        for (int q = 1; q < 8; ++q) {
            float4 v = sh[q][f4];
            tot.x += v.x; tot.y += v.y; tot.z += v.z; tot.w += v.w;
        }
        float inv = 1.0f / fmaxf((float)(e - s), 1.0f);
        tot.x *= inv; tot.y *= inv; tot.z *= inv; tot.w *= inv;
        ((float4*)pooled)[g * 32 + f4] = tot;
    }
}

__global__ void final_kernel(const float* __restrict__ pooled,
                             const float* __restrict__ Wlin, const float* __restrict__ blin,
                             float* __restrict__ out) {
    int idx = blockIdx.x * blockDim.x + threadIdx.x;   // 2048 = 128 x 16
    int g = idx >> 4, c = idx & 15;
    float s = 0.f;
    for (int k = 0; k < 128; ++k) s += pooled[g * 128 + k] * Wlin[c * 128 + k];
    out[idx] = s + blin[c];
}

// ---------------- launch ----------------
extern "C" void kernel_launch(void* const* d_in, const int* in_sizes, int n_in,
                              void* d_out, int out_size, void* d_ws, size_t ws_size,
                              hipStream_t stream) {
    const float* x      = (const float*)d_in[0];
    const int*   ei     = (const int*)d_in[1];
    const int*   batch  = (const int*)d_in[2];
    const float* W1_rel = (const float*)d_in[3];
    const float* b1     = (const float*)d_in[4];
    const float* W1_root= (const float*)d_in[5];
    const float* W2_rel = (const float*)d_in[6];
    const float* b2     = (const float*)d_in[7];
    const float* W2_root= (const float*)d_in[8];
    const float* W3_rel = (const float*)d_in[9];
    const float* b3     = (const float*)d_in[10];
    const float* W3_root= (const float*)d_in[11];
    const float* W_lin  = (const float*)d_in[12];
    const float* b_lin  = (const float*)d_in[13];
    float* out = (float*)d_out;

    const int N = in_sizes[2];          // 100000
    const int E = in_sizes[1] / 2;      // 1600000
    const int nb = (N + 511) / 512;

    char* base = (char*)d_ws;
    size_t off = 0;
    auto carve = [&](size_t bytes) -> void* {
        void* p = base + off;
        off = (off + bytes + 255) & ~(size_t)255;
        return p;
    };
    int*      deg    = (int*)carve((size_t)N * 4);
    int*      tmp    = (int*)carve((size_t)N * 4);
    int*      bsum   = (int*)carve(1024);
    int*      rowp   = (int*)carve((size_t)(N + 1) * 4);
    int*      rowpm  = (int*)carve((size_t)N * 4);
    int*      csr    = (int*)carve((size_t)E * 4);
    float*    aggbuf = (float*)carve((size_t)N * 128 * 4);
    float*    hA     = (float*)carve((size_t)N * 128 * 4);
    float*    hB     = (float*)carve((size_t)N * 128 * 4);
    float*    pooled = (float*)carve((size_t)N_GRAPHS_C * 128 * 4);
    int*      gstart = (int*)carve((size_t)(N_GRAPHS_C + 1) * 4);
    unsigned* wimg1  = (unsigned*)carve((size_t)4 * 4096 * 4);   // 64 KB
    unsigned* wimg2  = (unsigned*)carve((size_t)8 * 4096 * 4);   // 128 KB
    unsigned* wimg3  = (unsigned*)carve((size_t)8 * 4096 * 4);   // 128 KB
    (void)ws_size;

    hipMemsetAsync(deg, 0, (size_t)N * 4, stream);

    // weight prep (tiny): grid = NC*8 (c,j) blocks x 64 lanes
    wprep_kernel<<<32, 64, 0, stream>>>(W1_rel, W1_root, 64, wimg1);
    wprep_kernel<<<64, 64, 0, stream>>>(W2_rel, W2_root, 128, wimg2);
    wprep_kernel<<<64, 64, 0, stream>>>(W3_rel, W3_root, 128, wimg3);

    // CSR build
    hist_kernel<<<(E + 255) / 256, 256, 0, stream>>>(ei, E, deg);
    scan1_kernel<<<nb, 512, 0, stream>>>(deg, N, tmp, bsum);
    scan2_kernel<<<1, 64, 0, stream>>>(bsum, nb);
    scan3_kernel<<<nb, 512, 0, stream>>>(tmp, bsum, N, rowp, rowpm);
    const int npass = (N + 8191) >> 13;
    fill_kernel<<<dim3((E + 256 * FILL_EPT - 1) / (256 * FILL_EPT), npass), 256, 0, stream>>>(
        ei, E, rowpm, csr);

    // graph boundaries (batch sorted)
    bounds_kernel<<<1, 192, 0, stream>>>(batch, N, gstart);

    const int aggGrid = (N + 3) / 4;     // 4 waves/block, wave per node
    const int xGrid = (N + 127) / 128;

    // layer 1 (KTOT = 64+64)
    agg_kernel<64><<<aggGrid, 256, 0, stream>>>(x, rowp, deg, csr, aggbuf, N);
    xform_kernel<128, true><<<xGrid, 256, 0, stream>>>(aggbuf, x, wimg1, b1, hA, N);

    // layer 2 (KTOT = 128+128)
    agg_kernel<128><<<aggGrid, 256, 0, stream>>>(hA, rowp, deg, csr, aggbuf, N);
    xform_kernel<256, true><<<xGrid, 256, 0, stream>>>(aggbuf, hA, wimg2, b2, hB, N);

    // layer 3 (KTOT = 128+128, no relu)
    agg_kernel<128><<<aggGrid, 256, 0, stream>>>(hB, rowp, deg, csr, aggbuf, N);
    xform_kernel<256, false><<<xGrid, 256, 0, stream>>>(aggbuf, hB, wimg3, b3, hA, N);

    // pooling + classifier (no atomics)
    pool2_kernel<<<N_GRAPHS_C, 256, 0, stream>>>(hA, gstart, pooled);
    final_kernel<<<8, 256, 0, stream>>>(pooled, W_lin, b_lin, out);
}

// Round 11
// 776.082 us; speedup vs baseline: 1.3903x; 1.0339x over previous
//
#include <hip/hip_runtime.h>

#define N_NODES_C 100000
#define N_GRAPHS_C 128

typedef __attribute__((ext_vector_type(8))) __bf16 bf16x8;
typedef __attribute__((ext_vector_type(4))) float f32x4;

__device__ __forceinline__ f32x4 mfma16(bf16x8 a, bf16x8 b, f32x4 c) {
    return __builtin_amdgcn_mfma_f32_16x16x32_bf16(a, b, c, 0, 0, 0);
}

// split two fp32 into packed bf16 hi-pair and lo-pair (low element in low 16 bits)
__device__ __forceinline__ void split2(float a, float b, unsigned& hi, unsigned& lo) {
    unsigned ua = __float_as_uint(a), ub = __float_as_uint(b);
    unsigned ha = ua & 0xFFFF0000u, hb = ub & 0xFFFF0000u;
    float la = a - __uint_as_float(ha), lb = b - __uint_as_float(hb);
    unsigned lpa = __float_as_uint(la) & 0xFFFF0000u;
    unsigned lpb = __float_as_uint(lb) & 0xFFFF0000u;
    hi = (ha >> 16) | hb;
    lo = (lpa >> 16) | lpb;
}

__device__ __forceinline__ void splitfrag(float4 v0, float4 v1, bf16x8& hi, bf16x8& lo) {
    unsigned h[4], l[4];
    split2(v0.x, v0.y, h[0], l[0]); split2(v0.z, v0.w, h[1], l[1]);
    split2(v1.x, v1.y, h[2], l[2]); split2(v1.z, v1.w, h[3], l[3]);
    uint4 uh = make_uint4(h[0], h[1], h[2], h[3]);
    uint4 ul = make_uint4(l[0], l[1], l[2], l[3]);
    hi = *(bf16x8*)&uh; lo = *(bf16x8*)&ul;
}

#define FILL_EPT 8

// ---------------- CSR build ----------------
// pass-confined histogram: pass p only touches deg[p*8192 .. p*8192+8191] (32 KB window)
__global__ void hist_kernel(const int* __restrict__ ei, int E, int* __restrict__ deg) {
    int p = blockIdx.y;
    int base = blockIdx.x * 256 * FILL_EPT + threadIdx.x;
#pragma unroll
    for (int k = 0; k < FILL_EPT; ++k) {
        int i = base + k * 256;
        if (i < E) {
            int d = ei[E + i];
            if ((d >> 13) == p) atomicAdd(&deg[d], 1);
        }
    }
}

__global__ void scan1_kernel(const int* __restrict__ deg, int N,
                             int* __restrict__ tmp, int* __restrict__ bsum) {
    __shared__ int sh[512];
    int t = threadIdx.x;
    int i = blockIdx.x * 512 + t;
    int v = (i < N) ? deg[i] : 0;
    sh[t] = v;
    __syncthreads();
    for (int off = 1; off < 512; off <<= 1) {
        int add = (t >= off) ? sh[t - off] : 0;
        __syncthreads();
        sh[t] += add;
        __syncthreads();
    }
    if (i < N) tmp[i] = sh[t] - v;
    if (t == 511) bsum[blockIdx.x] = sh[511];
}

// parallel scan over block sums (nb <= 512), replaces serial single-thread loop
__global__ void scan2_kernel(int* bsum, int nb) {
    __shared__ int sh[512];
    int t = threadIdx.x;
    int v = (t < nb) ? bsum[t] : 0;
    sh[t] = v;
    __syncthreads();
    for (int off = 1; off < 512; off <<= 1) {
        int add = (t >= off) ? sh[t - off] : 0;
        __syncthreads();
        sh[t] += add;
        __syncthreads();
    }
    if (t < nb) bsum[t] = sh[t] - v;    // exclusive
}

__global__ void scan3_kernel(const int* __restrict__ tmp, const int* __restrict__ bsum,
                             int N, int* __restrict__ rowp, int* __restrict__ rowpm) {
    int i = blockIdx.x * 512 + threadIdx.x;
    if (i < N) {
        int v = tmp[i] + bsum[blockIdx.x];
        rowp[i] = v;
        rowpm[i] = v;          // mutable copy consumed by fill as cursor
    }
}

// dst-range passes: csr writes and rowpm atomics confined to an L2-resident window.
__global__ void fill_kernel(const int* __restrict__ ei, int E,
                            int* __restrict__ rowpm, int* __restrict__ csr) {
    int p = blockIdx.y;
    int base = blockIdx.x * 256 * FILL_EPT + threadIdx.x;
#pragma unroll
    for (int k = 0; k < FILL_EPT; ++k) {
        int i = base + k * 256;
        if (i < E) {
            int d = ei[E + i];
            if ((d >> 13) == p) {
                int pos = atomicAdd(&rowpm[d], 1);
                csr[pos] = ei[i];                    // src row
            }
        }
    }
}

// ---------------- neighbor aggregation (float4 gather, always-8-deep ILP) ------
// FIN==128: EPW=2 edges per wave-instr; FIN==64: EPW=4. Inner loop issues 8
// predicated loads in flight regardless of degree (clamped shfl index).
template <int FIN>
__global__ __launch_bounds__(256) void agg_kernel(const float* __restrict__ xin,
                                                  const int* __restrict__ rowp,
                                                  const int* __restrict__ degv,
                                                  const int* __restrict__ csrc,
                                                  float* __restrict__ aggout, int nNodes) {
    int wave = blockIdx.x * 4 + (threadIdx.x >> 6);
    int lane = threadIdx.x & 63;
    if (wave >= nNodes) return;
    int start = rowp[wave];
    int deg = degv[wave];
    const float4* x4 = (const float4*)xin;
    constexpr int EPW = (FIN == 128) ? 2 : 4;       // edges per wave-iteration
    constexpr int RS = FIN / 4;                      // float4s per row (32 or 16)
    const int grp = lane / RS;                       // which edge in the group
    const int f4 = lane & (RS - 1);                  // float4 index within row

    float4 acc[8];
#pragma unroll
    for (int q = 0; q < 8; ++q) acc[q] = make_float4(0.f, 0.f, 0.f, 0.f);

    for (int base = 0; base < deg; base += 64) {
        int cnt = min(64, deg - base);
        int sid = (lane < cnt) ? csrc[start + base + lane] : 0;
        for (int j = 0; j < cnt; j += 8 * EPW) {
            int rem = cnt - j;                       // > 0
            int n[8];
#pragma unroll
            for (int q = 0; q < 8; ++q) {
                int e = q * EPW + grp;
                n[q] = __shfl(sid, j + min(e, rem - 1));   // clamped: always valid
            }
            float4 v[8];
#pragma unroll
            for (int q = 0; q < 8; ++q) v[q] = x4[(size_t)n[q] * RS + f4];
#pragma unroll
            for (int q = 0; q < 8; ++q) {
                if (q * EPW + grp < rem) {
                    acc[q].x += v[q].x; acc[q].y += v[q].y;
                    acc[q].z += v[q].z; acc[q].w += v[q].w;
                }
            }
        }
    }
    float4 tot;
    tot.x = ((acc[0].x+acc[1].x)+(acc[2].x+acc[3].x)) + ((acc[4].x+acc[5].x)+(acc[6].x+acc[7].x));
    tot.y = ((acc[0].y+acc[1].y)+(acc[2].y+acc[3].y)) + ((acc[4].y+acc[5].y)+(acc[6].y+acc[7].y));
    tot.z = ((acc[0].z+acc[1].z)+(acc[2].z+acc[3].z)) + ((acc[4].z+acc[5].z)+(acc[6].z+acc[7].z));
    tot.w = ((acc[0].w+acc[1].w)+(acc[2].w+acc[3].w)) + ((acc[4].w+acc[5].w)+(acc[6].w+acc[7].w));
    if (FIN == 64) {
        tot.x += __shfl_xor(tot.x, 16); tot.y += __shfl_xor(tot.y, 16);
        tot.z += __shfl_xor(tot.z, 16); tot.w += __shfl_xor(tot.w, 16);
    }
    tot.x += __shfl_xor(tot.x, 32); tot.y += __shfl_xor(tot.y, 32);
    tot.z += __shfl_xor(tot.z, 32); tot.w += __shfl_xor(tot.w, 32);
    if (lane < RS)
        ((float4*)aggout)[(size_t)wave * RS + lane] = tot;
}

// ---------------- weight prep: frag-linear split-bf16 W image ----------------
// For chunk c, out-tile j, plane p (0=hi,1=lo): 1 KB block, lane l's bf16x8 at l*16B.
// Frag layout (m89): col = j*16 + (l&15), k = c*32 + (l>>4)*8 + e, pairs packed lo/hi.
__global__ void wprep_kernel(const float* __restrict__ Wrel, const float* __restrict__ Wroot,
                             int KH, unsigned* __restrict__ img) {
    int cj = blockIdx.x;               // c*8 + j
    int l = threadIdx.x;               // 0..63
    int c = cj >> 3, j = cj & 7;
    int col = j * 16 + (l & 15);
    int k0 = c * 32 + (l >> 4) * 8;
    const float* src = (k0 < KH) ? Wrel : Wroot;
    int kk = (k0 < KH) ? k0 : k0 - KH;
    unsigned h[4], lo[4];
#pragma unroll
    for (int q = 0; q < 4; ++q) {
        float a = src[col * KH + kk + 2 * q];
        float b = src[col * KH + kk + 2 * q + 1];
        split2(a, b, h[q], lo[q]);
    }
    *(uint4*)&img[((size_t)cj * 2 + 0) * 256 + l * 4] = make_uint4(h[0], h[1], h[2], h[3]);
    *(uint4*)&img[((size_t)cj * 2 + 1) * 256 + l * 4] = make_uint4(lo[0], lo[1], lo[2], lo[3]);
}

// ---------------- dual-GEMM transform: zero-LDS register-direct MFMA ----------------
template <int KTOT, bool RELU>
__global__ __launch_bounds__(256) void xform_kernel(
    const float* __restrict__ agg, const float* __restrict__ xin,
    const unsigned* __restrict__ wimg, const float* __restrict__ bias,
    float* __restrict__ hout, int nNodes)
{
    constexpr int KH = KTOT / 2;
    constexpr int NC = KTOT / 32;
    const int t = threadIdx.x;
    const int lane = t & 63, wv = t >> 6;
    const int r15 = lane & 15, hi4 = lane >> 4;
    const int nb0 = blockIdx.x * 128;
    const int row0 = nb0 + wv * 32 + r15;
    const int row1 = row0 + 16;
    const bool v0 = row0 < nNodes, v1 = row1 < nNodes;
    const float4 z4 = make_float4(0.f, 0.f, 0.f, 0.f);

    f32x4 acc[2][8];
#pragma unroll
    for (int g = 0; g < 2; ++g)
#pragma unroll
        for (int j = 0; j < 8; ++j) acc[g][j] = (f32x4){0.f, 0.f, 0.f, 0.f};
    float bj[8];
#pragma unroll
    for (int j = 0; j < 8; ++j) bj[j] = bias[j * 16 + r15];

#pragma unroll 1
    for (int c = 0; c < NC; ++c) {
        const float* srcA = (c * 32 < KH) ? agg : xin;
        const int ko = ((c * 32 < KH) ? (c * 32) : (c * 32 - KH)) + hi4 * 8;
        const float* p0 = &srcA[(size_t)row0 * KH + ko];
        const float* p1 = &srcA[(size_t)row1 * KH + ko];
        float4 a00 = v0 ? *(const float4*)p0 : z4;
        float4 a01 = v0 ? *(const float4*)(p0 + 4) : z4;
        float4 a10 = v1 ? *(const float4*)p1 : z4;
        float4 a11 = v1 ? *(const float4*)(p1 + 4) : z4;
        bf16x8 ah0, al0, ah1, al1;
        splitfrag(a00, a01, ah0, al0);
        splitfrag(a10, a11, ah1, al1);
        const unsigned* wc = wimg + (size_t)c * 4096;   // 8 j x 2 planes x 256 uints
#pragma unroll
        for (int j = 0; j < 8; ++j) {
            bf16x8 bh = *(const bf16x8*)&wc[(j * 2 + 0) * 256 + lane * 4];
            bf16x8 bl = *(const bf16x8*)&wc[(j * 2 + 1) * 256 + lane * 4];
            acc[0][j] = mfma16(ah0, bh, acc[0][j]);
            acc[1][j] = mfma16(ah1, bh, acc[1][j]);
            acc[0][j] = mfma16(ah0, bl, acc[0][j]);
            acc[1][j] = mfma16(ah1, bl, acc[1][j]);
            acc[0][j] = mfma16(al0, bh, acc[0][j]);
            acc[1][j] = mfma16(al1, bh, acc[1][j]);
        }
    }

    // epilogue: C col=lane&15 (out channel), row=(lane>>4)*4+reg (node) — m89-verified
#pragma unroll
    for (int g2 = 0; g2 < 2; ++g2) {
#pragma unroll
        for (int r = 0; r < 4; ++r) {
            int node = nb0 + wv * 32 + g2 * 16 + hi4 * 4 + r;
            if (node >= nNodes) continue;
            float* orow = &hout[(size_t)node * 128];
#pragma unroll
            for (int j = 0; j < 8; ++j) {
                float v = acc[g2][j][r] + bj[j];
                if (RELU) v = fmaxf(v, 0.f);
                orow[j * 16 + r15] = v;
            }
        }
    }
}

// ---------------- pooling (batch is SORTED: geometry, no atomics) ----------------
__global__ void bounds_kernel(const int* __restrict__ batch, int N, int* __restrict__ gstart) {
    int g = blockIdx.x * blockDim.x + threadIdx.x;
    if (g > N_GRAPHS_C) return;
    int lo = 0, hi = N;
    while (lo < hi) {
        int mid = (lo + hi) >> 1;
        if (batch[mid] < g) lo = mid + 1; else hi = mid;
    }
    gstart[g] = lo;
}

// one block per graph; 256 threads = 8 node-subsets x 32 float4-features
__global__ __launch_bounds__(256) void pool2_kernel(const float* __restrict__ h,
                                                    const int* __restrict__ gstart,
                                                    float* __restrict__ pooled) {
    int g = blockIdx.x;
    int f4 = threadIdx.x & 31;
    int sub = threadIdx.x >> 5;
    int s = gstart[g], e = gstart[g + 1];
    const float4* h4 = (const float4*)h;
    float4 acc = make_float4(0.f, 0.f, 0.f, 0.f);
    for (int n = s + sub; n < e; n += 8) {
        float4 v = h4[(size_t)n * 32 + f4];
        acc.x += v.x; acc.y += v.y; acc.z += v.z; acc.w += v.w;
    }
    __shared__ float4 sh[8][33];
    sh[sub][f4] = acc;
    __syncthreads();
    if (sub == 0) {
        float4 tot = acc;
#pragma unroll
        for (int q = 1; q < 8; ++q) {
            float4 v = sh[q][f4];
            tot.x += v.x; tot.y += v.y; tot.z += v.z; tot.w += v.w;
        }
        float inv = 1.0f / fmaxf((float)(e - s), 1.0f);
        tot.x *= inv; tot.y *= inv; tot.z *= inv; tot.w *= inv;
        ((float4*)pooled)[g * 32 + f4] = tot;
    }
}

__global__ void final_kernel(const float* __restrict__ pooled,
                             const float* __restrict__ Wlin, const float* __restrict__ blin,
                             float* __restrict__ out) {
    int idx = blockIdx.x * blockDim.x + threadIdx.x;   // 2048 = 128 x 16
    int g = idx >> 4, c = idx & 15;
    float s = 0.f;
    for (int k = 0; k < 128; ++k) s += pooled[g * 128 + k] * Wlin[c * 128 + k];
    out[idx] = s + blin[c];
}

// ---------------- launch ----------------
extern "C" void kernel_launch(void* const* d_in, const int* in_sizes, int n_in,
                              void* d_out, int out_size, void* d_ws, size_t ws_size,
                              hipStream_t stream) {
    const float* x      = (const float*)d_in[0];
    const int*   ei     = (const int*)d_in[1];
    const int*   batch  = (const int*)d_in[2];
    const float* W1_rel = (const float*)d_in[3];
    const float* b1     = (const float*)d_in[4];
    const float* W1_root= (const float*)d_in[5];
    const float* W2_rel = (const float*)d_in[6];
    const float* b2     = (const float*)d_in[7];
    const float* W2_root= (const float*)d_in[8];
    const float* W3_rel = (const float*)d_in[9];
    const float* b3     = (const float*)d_in[10];
    const float* W3_root= (const float*)d_in[11];
    const float* W_lin  = (const float*)d_in[12];
    const float* b_lin  = (const float*)d_in[13];
    float* out = (float*)d_out;

    const int N = in_sizes[2];          // 100000
    const int E = in_sizes[1] / 2;      // 1600000
    const int nb = (N + 511) / 512;

    char* base = (char*)d_ws;
    size_t off = 0;
    auto carve = [&](size_t bytes) -> void* {
        void* p = base + off;
        off = (off + bytes + 255) & ~(size_t)255;
        return p;
    };
    int*      deg    = (int*)carve((size_t)N * 4);
    int*      tmp    = (int*)carve((size_t)N * 4);
    int*      bsum   = (int*)carve(2048);
    int*      rowp   = (int*)carve((size_t)(N + 1) * 4);
    int*      rowpm  = (int*)carve((size_t)N * 4);
    int*      csr    = (int*)carve((size_t)E * 4);
    float*    aggbuf = (float*)carve((size_t)N * 128 * 4);
    float*    hA     = (float*)carve((size_t)N * 128 * 4);
    float*    hB     = (float*)carve((size_t)N * 128 * 4);
    float*    pooled = (float*)carve((size_t)N_GRAPHS_C * 128 * 4);
    int*      gstart = (int*)carve((size_t)(N_GRAPHS_C + 1) * 4);
    unsigned* wimg1  = (unsigned*)carve((size_t)4 * 4096 * 4);   // 64 KB
    unsigned* wimg2  = (unsigned*)carve((size_t)8 * 4096 * 4);   // 128 KB
    unsigned* wimg3  = (unsigned*)carve((size_t)8 * 4096 * 4);   // 128 KB
    (void)ws_size;

    hipMemsetAsync(deg, 0, (size_t)N * 4, stream);

    // weight prep (tiny): grid = NC*8 (c,j) blocks x 64 lanes
    wprep_kernel<<<32, 64, 0, stream>>>(W1_rel, W1_root, 64, wimg1);
    wprep_kernel<<<64, 64, 0, stream>>>(W2_rel, W2_root, 128, wimg2);
    wprep_kernel<<<64, 64, 0, stream>>>(W3_rel, W3_root, 128, wimg3);

    // CSR build (pass-confined atomics for hist and fill)
    const int npass = (N + 8191) >> 13;
    const int fillGx = (E + 256 * FILL_EPT - 1) / (256 * FILL_EPT);
    hist_kernel<<<dim3(fillGx, npass), 256, 0, stream>>>(ei, E, deg);
    scan1_kernel<<<nb, 512, 0, stream>>>(deg, N, tmp, bsum);
    scan2_kernel<<<1, 512, 0, stream>>>(bsum, nb);
    scan3_kernel<<<nb, 512, 0, stream>>>(tmp, bsum, N, rowp, rowpm);
    fill_kernel<<<dim3(fillGx, npass), 256, 0, stream>>>(ei, E, rowpm, csr);

    // graph boundaries (batch sorted)
    bounds_kernel<<<1, 192, 0, stream>>>(batch, N, gstart);

    const int aggGrid = (N + 3) / 4;     // 4 waves/block, wave per node
    const int xGrid = (N + 127) / 128;

    // layer 1 (KTOT = 64+64)
    agg_kernel<64><<<aggGrid, 256, 0, stream>>>(x, rowp, deg, csr, aggbuf, N);
    xform_kernel<128, true><<<xGrid, 256, 0, stream>>>(aggbuf, x, wimg1, b1, hA, N);

    // layer 2 (KTOT = 128+128)
    agg_kernel<128><<<aggGrid, 256, 0, stream>>>(hA, rowp, deg, csr, aggbuf, N);
    xform_kernel<256, true><<<xGrid, 256, 0, stream>>>(aggbuf, hA, wimg2, b2, hB, N);

    // layer 3 (KTOT = 128+128, no relu)
    agg_kernel<128><<<aggGrid, 256, 0, stream>>>(hB, rowp, deg, csr, aggbuf, N);
    xform_kernel<256, false><<<xGrid, 256, 0, stream>>>(aggbuf, hB, wimg3, b3, hA, N);

    // pooling + classifier (no atomics)
    pool2_kernel<<<N_GRAPHS_C, 256, 0, stream>>>(hA, gstart, pooled);
    final_kernel<<<8, 256, 0, stream>>>(pooled, W_lin, b_lin, out);
}